// Round 5
// baseline (142.043 us; speedup 1.0000x reference)
//
#include <hip/hip_runtime.h>
#include <hip/hip_bf16.h>

// MPNNConv restructured:
//   s[n] = h[n] @ W1[0:128] + b1 (f32 swz), g[n] = h[n] @ W1[128:256] (bf16 swz, L2-resident)
//   Hsum[n] = sum_{e: rows[e]=n} relu(s[n] + g[cols[e]] + ef[e] @ W1e)   (K=32 MFMA)
//   out[n]  = Hsum[n] @ W2 + deg[n]*b2
// CSR on-device (hist/rank -> scan -> ec scatter). layer1 gathers ef f32
// directly: one edge = one 128B line read exactly once (2 waves/node split
// by EDGES, each wave covers all 128 output cols -> no duplicate gathers).

typedef __attribute__((ext_vector_type(8))) short bf16x8;
typedef __attribute__((ext_vector_type(4))) float f32x4;

#define ND 128
#define ED 32

__device__ __forceinline__ short f2bf(float x) {
  unsigned int u = __float_as_uint(x);
  unsigned int r = (u + 0x7FFFu + ((u >> 16) & 1u)) >> 16;
  return (short)r;
}

__device__ __forceinline__ float bf2f(short s) {
  return __uint_as_float(((unsigned int)(unsigned short)s) << 16);
}

__device__ __forceinline__ f32x4 bf8lo(bf16x8 v) {
  f32x4 r;
  #pragma unroll
  for (int j = 0; j < 4; ++j) r[j] = bf2f(v[j]);
  return r;
}
__device__ __forceinline__ f32x4 bf8hi(bf16x8 v) {
  f32x4 r;
  #pragma unroll
  for (int j = 0; j < 4; ++j) r[j] = bf2f(v[4 + j]);
  return r;
}

__device__ __forceinline__ int load_idx(const void* ei, long long i, int is64) {
  return is64 ? (int)((const long long*)ei)[i] : ((const int*)ei)[i];
}

__device__ __forceinline__ int detect64(const void* ei) {
  const unsigned int* u = (const unsigned int*)ei;
  int is64 = 1;
  #pragma unroll
  for (int i = 0; i < 16; ++i)
    if (u[2 * i + 1] != 0u) is64 = 0;
  return is64;
}

// swizzled offset within a 128-wide row for col c (c = ct*16 + cc):
// o = (ct>>2)*64 + (cc>>2)*16 + (ct&3)*4 + (cc&3)
__device__ __forceinline__ int swz(int c) {
  int ct = c >> 4, cc = c & 15;
  return (ct >> 2) * 64 + (cc >> 2) * 16 + (ct & 3) * 4 + (cc & 3);
}

// --- fused: weight pre-layouts (blocks [0,128)) + histogram/rank (rest) ---
__global__ __launch_bounds__(256) void prep_hist_kernel(
    const float* __restrict__ W1, const float* __restrict__ W2,
    const void* __restrict__ ei, int* __restrict__ counts,
    int* __restrict__ rank, short* __restrict__ w12t,
    short* __restrict__ w1eA, short* __restrict__ w2t, int E) {
  int b = blockIdx.x;
  if (b < 128) {
    int t = b * 256 + threadIdx.x;
    if (t < 256 * 128) {
      int np = t >> 7, k = t & 127;
      float v = (np < 128) ? W1[k * 128 + np] : W1[(128 + k) * 128 + (np - 128)];
      w12t[t] = f2bf(v);
    }
    if (t < 128 * 128) {
      int n = t >> 7, k = t & 127;
      w2t[t] = f2bf(W2[k * 128 + n]);
    }
    if (t < 8 * 64 * 8) {  // w1eA[ct][lane][j] = W1[256+lg*8+j][ct*16+li]
      int ct = t >> 9, lane = (t >> 3) & 63, j = t & 7;
      int li = lane & 15, lg = lane >> 4;
      w1eA[t] = f2bf(W1[(256 + lg * 8 + j) * 128 + ct * 16 + li]);
    }
  } else {
    int e = (b - 128) * 256 + threadIdx.x;
    if (e < E) {
      int is64 = detect64(ei);
      int r = load_idx(ei, e, is64);
      rank[e] = atomicAdd(&counts[r], 1);
    }
  }
}

// --- single-block scan: 1024 threads x 16 elems ---
__global__ __launch_bounds__(1024) void scan_kernel(const int* __restrict__ counts,
                                                    int* __restrict__ row_ptr, int n) {
  __shared__ int wtot[16];
  int tid = threadIdx.x;
  int lane = tid & 63, w = tid >> 6;
  int base_i = tid * 16;
  int c[16];
  int tot = 0;
  #pragma unroll
  for (int j = 0; j < 16; ++j) {
    int i = base_i + j;
    c[j] = (i < n) ? counts[i] : 0;
    tot += c[j];
  }
  int x = tot;
  #pragma unroll
  for (int d = 1; d < 64; d <<= 1) {
    int t = __shfl_up(x, d);
    if (lane >= d) x += t;
  }
  if (lane == 63) wtot[w] = x;
  __syncthreads();
  if (w == 0) {
    int y = (lane < 16) ? wtot[lane] : 0;
    #pragma unroll
    for (int d = 1; d < 16; d <<= 1) {
      int t = __shfl_up(y, d);
      if (lane >= d) y += t;
    }
    if (lane < 16) wtot[lane] = y;
  }
  __syncthreads();
  int waveoff = (w == 0) ? 0 : wtot[w - 1];
  int run = waveoff + x - tot;  // exclusive prefix
  if (tid == 0) row_ptr[0] = 0;
  #pragma unroll
  for (int j = 0; j < 16; ++j) {
    int i = base_i + j;
    if (i < n) {
      run += c[j];
      row_ptr[i + 1] = run;
    }
  }
}

// --- fused: sg GEMM (blocks [0,SGB)) + ec scatter (rest, 1 thread/edge) ---
__global__ __launch_bounds__(256, 4) void scatter_sg_kernel(
    const void* __restrict__ ei, const int* __restrict__ row_ptr,
    const int* __restrict__ rank, const float* __restrict__ h,
    const short* __restrict__ w12t, const float* __restrict__ b1,
    int2* __restrict__ ec, float* __restrict__ s2, short* __restrict__ g2,
    int N, int E) {
  int b = blockIdx.x;
  int SGB = (N + 63) >> 6;
  if (b < SGB) {
    int lane = threadIdx.x & 63, w = threadIdx.x >> 6;
    int li = lane & 15, lg = lane >> 4;
    int base = b * 64 + w * 16;
    int rowm = base + li;
    if (rowm >= N) rowm = N - 1;
    float breg[8];
    #pragma unroll
    for (int nt = 0; nt < 8; ++nt) breg[nt] = b1[nt * 16 + li];
    f32x4 acc[16];
    #pragma unroll
    for (int nt = 0; nt < 16; ++nt) acc[nt] = (f32x4){0.f, 0.f, 0.f, 0.f};
    #pragma unroll
    for (int kc = 0; kc < 4; ++kc) {
      f32x4 f0 = *(const f32x4*)(h + (size_t)rowm * ND + kc * 32 + lg * 8);
      f32x4 f1 = *(const f32x4*)(h + (size_t)rowm * ND + kc * 32 + lg * 8 + 4);
      bf16x8 a;
      #pragma unroll
      for (int j = 0; j < 4; ++j) { a[j] = f2bf(f0[j]); a[4 + j] = f2bf(f1[j]); }
      #pragma unroll
      for (int nt = 0; nt < 16; ++nt) {
        bf16x8 bb = *(const bf16x8*)(w12t + (nt * 16 + li) * 128 + kc * 32 + lg * 8);
        acc[nt] = __builtin_amdgcn_mfma_f32_16x16x32_bf16(a, bb, acc[nt], 0, 0, 0);
      }
    }
    #pragma unroll
    for (int nt = 0; nt < 16; ++nt)
      #pragma unroll
      for (int r = 0; r < 4; ++r) {
        int row = base + lg * 4 + r;
        if (row < N) {
          if (nt < 8) {
            s2[(size_t)row * 128 + swz(nt * 16 + li)] = acc[nt][r] + breg[nt];
          } else {
            g2[(size_t)row * 128 + swz((nt - 8) * 16 + li)] = f2bf(acc[nt][r]);
          }
        }
      }
  } else {
    int e = (b - SGB) * 256 + threadIdx.x;
    if (e < E) {
      int is64 = detect64(ei);
      int r = load_idx(ei, e, is64);
      int c = load_idx(ei, (long long)E + e, is64);
      ec[row_ptr[r] + rank[e]] = make_int2(e, c);
    }
  }
}

// --- layer 1 + segment reduce: 2 waves/node split by EDGES, all 128 cols/wave ---
__global__ __launch_bounds__(128) void layer1_kernel(
    const float* __restrict__ s2, const short* __restrict__ g2,
    const float* __restrict__ ef, const int2* __restrict__ ec,
    const short* __restrict__ w1eA, const int* __restrict__ row_ptr,
    float* __restrict__ hsum) {
  int node = blockIdx.x;
  int lane = threadIdx.x & 63;
  int w = threadIdx.x >> 6;  // edge-half (tiles t = w, w+2, ...)
  int li = lane & 15, lg = lane >> 4;
  int rp = row_ptr[node], rpe = row_ptr[node + 1];
  int deg = rpe - rp;
  __shared__ float red[128];

  f32x4 psum[8];
  #pragma unroll
  for (int ct = 0; ct < 8; ++ct) psum[ct] = (f32x4){0.f, 0.f, 0.f, 0.f};

  if (deg > 0) {
    bf16x8 wa[8];
    #pragma unroll
    for (int ct = 0; ct < 8; ++ct)
      wa[ct] = *(const bf16x8*)(w1eA + ((ct * 64 + lane) * 8));
    f32x4 sreg[8];
    #pragma unroll
    for (int ct = 0; ct < 8; ++ct)
      sreg[ct] = *(const f32x4*)(s2 + (size_t)node * 128 + (ct >> 2) * 64 + lg * 16 + (ct & 3) * 4);

    int ntiles = (deg + 15) >> 4;
    int last = rpe - 1;
    auto ppos = [&](int t) {
      int p = rp + t * 16 + li;
      return p > last ? last : p;
    };

    int2 iA = ec[ppos(w)];
    int2 iB = ec[ppos(w + 2)];
    f32x4 eA0 = *(const f32x4*)(ef + (size_t)iA.x * ED + lg * 8);
    f32x4 eA1 = *(const f32x4*)(ef + (size_t)iA.x * ED + lg * 8 + 4);
    const short* gpA = g2 + (size_t)iA.y * 128;
    bf16x8 gA00 = *(const bf16x8*)(gpA + lg * 16);
    bf16x8 gA01 = *(const bf16x8*)(gpA + lg * 16 + 8);
    bf16x8 gA10 = *(const bf16x8*)(gpA + 64 + lg * 16);
    bf16x8 gA11 = *(const bf16x8*)(gpA + 64 + lg * 16 + 8);

    for (int t = w; t < ntiles; t += 2) {
      int2 iC = ec[ppos(t + 4)];
      // prefetch next tile payloads (hide under this tile's compute)
      f32x4 eB0 = *(const f32x4*)(ef + (size_t)iB.x * ED + lg * 8);
      f32x4 eB1 = *(const f32x4*)(ef + (size_t)iB.x * ED + lg * 8 + 4);
      const short* gpB = g2 + (size_t)iB.y * 128;
      bf16x8 gB00 = *(const bf16x8*)(gpB + lg * 16);
      bf16x8 gB01 = *(const bf16x8*)(gpB + lg * 16 + 8);
      bf16x8 gB10 = *(const bf16x8*)(gpB + 64 + lg * 16);
      bf16x8 gB11 = *(const bf16x8*)(gpB + 64 + lg * 16 + 8);
      // current tile
      bf16x8 bfrag;
      #pragma unroll
      for (int j = 0; j < 4; ++j) { bfrag[j] = f2bf(eA0[j]); bfrag[4 + j] = f2bf(eA1[j]); }
      f32x4 acc[8];
      #pragma unroll
      for (int ct = 0; ct < 8; ++ct)
        acc[ct] = __builtin_amdgcn_mfma_f32_16x16x32_bf16(wa[ct], bfrag,
                                                          (f32x4){0.f, 0.f, 0.f, 0.f}, 0, 0, 0);
      if ((t * 16 + li) < deg) {
        #pragma unroll
        for (int ct = 0; ct < 8; ++ct) {
          bf16x8 gr = (ct < 4) ? ((ct & 2) ? gA01 : gA00) : ((ct & 2) ? gA11 : gA10);
          f32x4 gv = (ct & 1) ? bf8hi(gr) : bf8lo(gr);
          f32x4 v = acc[ct] + sreg[ct] + gv;
          #pragma unroll
          for (int r = 0; r < 4; ++r)
            psum[ct][r] += (v[r] > 0.f ? v[r] : 0.f);
        }
      }
      iA = iB; iB = iC;
      eA0 = eB0; eA1 = eB1;
      gA00 = gB00; gA01 = gB01; gA10 = gB10; gA11 = gB11;
    }
  }

  // reduce across the 16 li-lanes (edges)
  #pragma unroll
  for (int ct = 0; ct < 8; ++ct)
    #pragma unroll
    for (int r = 0; r < 4; ++r) {
      float v = psum[ct][r];
      v += __shfl_xor(v, 1);
      v += __shfl_xor(v, 2);
      v += __shfl_xor(v, 4);
      v += __shfl_xor(v, 8);
      psum[ct][r] = v;
    }
  // combine the two waves via LDS
  if (w == 1 && li == 0) {
    #pragma unroll
    for (int ct = 0; ct < 8; ++ct)
      *(f32x4*)(red + ct * 16 + lg * 4) = psum[ct];
  }
  __syncthreads();
  if (w == 0 && li == 0) {
    #pragma unroll
    for (int ct = 0; ct < 8; ++ct) {
      f32x4 o = psum[ct] + *(const f32x4*)(red + ct * 16 + lg * 4);
      *(f32x4*)(hsum + (size_t)node * 128 + ct * 16 + lg * 4) = o;
    }
  }
}

// --- out = Hsum @ W2 + deg*b2 ; 4 waves x 16 rows per block ---
__global__ __launch_bounds__(256) void out_kernel(const float* __restrict__ hsum,
                                                  const short* __restrict__ w2t,
                                                  const float* __restrict__ b2,
                                                  const int* __restrict__ row_ptr,
                                                  float* __restrict__ out, int N) {
  int lane = threadIdx.x & 63, w = threadIdx.x >> 6;
  int li = lane & 15, lg = lane >> 4;
  int base = blockIdx.x * 64 + w * 16;
  int rowm = base + li;
  if (rowm >= N) rowm = N - 1;
  float breg[8];
  #pragma unroll
  for (int nt = 0; nt < 8; ++nt) breg[nt] = b2[nt * 16 + li];
  f32x4 acc[8];
  #pragma unroll
  for (int nt = 0; nt < 8; ++nt) acc[nt] = (f32x4){0.f, 0.f, 0.f, 0.f};
  #pragma unroll
  for (int kc = 0; kc < 4; ++kc) {
    f32x4 f0 = *(const f32x4*)(hsum + (size_t)rowm * 128 + kc * 32 + lg * 8);
    f32x4 f1 = *(const f32x4*)(hsum + (size_t)rowm * 128 + kc * 32 + lg * 8 + 4);
    bf16x8 a;
    #pragma unroll
    for (int j = 0; j < 4; ++j) { a[j] = f2bf(f0[j]); a[4 + j] = f2bf(f1[j]); }
    #pragma unroll
    for (int nt = 0; nt < 8; ++nt) {
      bf16x8 bb = *(const bf16x8*)(w2t + (nt * 16 + li) * 128 + kc * 32 + lg * 8);
      acc[nt] = __builtin_amdgcn_mfma_f32_16x16x32_bf16(a, bb, acc[nt], 0, 0, 0);
    }
  }
  #pragma unroll
  for (int r = 0; r < 4; ++r) {
    int row = base + lg * 4 + r;
    if (row < N) {
      float dg = (float)(row_ptr[row + 1] - row_ptr[row]);
      #pragma unroll
      for (int nt = 0; nt < 8; ++nt)
        out[(size_t)row * 128 + nt * 16 + li] = acc[nt][r] + dg * breg[nt];
    }
  }
}

extern "C" void kernel_launch(void* const* d_in, const int* in_sizes, int n_in,
                              void* d_out, int out_size, void* d_ws, size_t ws_size,
                              hipStream_t stream) {
  const void*  ei = d_in[1];
  const float* ef = (const float*)d_in[2];
  const float* h  = (const float*)d_in[0];
  const float* W1 = (const float*)d_in[4];
  const float* b1 = (const float*)d_in[5];
  const float* W2 = (const float*)d_in[6];
  const float* b2 = (const float*)d_in[7];
  float* out = (float*)d_out;
  int N = in_sizes[0] / ND;
  int E = in_sizes[2] / ED;

  char* ws = (char*)d_ws;
  size_t off = 0;
  auto alloc = [&](size_t bytes) {
    size_t o = off;
    off = (off + bytes + 255) & ~(size_t)255;
    return o;
  };
  int*   counts  = (int*)(ws + alloc((size_t)N * 4));
  int*   row_ptr = (int*)(ws + alloc((size_t)(N + 1) * 4));
  int*   rank    = (int*)(ws + alloc((size_t)E * 4));
  short* w12t    = (short*)(ws + alloc(256 * 128 * 2));
  short* w1eA    = (short*)(ws + alloc(8 * 64 * 8 * 2));
  short* w2t     = (short*)(ws + alloc(128 * 128 * 2));
  float* s2      = (float*)(ws + alloc((size_t)N * 128 * 4));
  short* g2      = (short*)(ws + alloc((size_t)N * 128 * 2));
  float* hsumb   = (float*)(ws + alloc((size_t)N * 128 * 4));
  int2*  ec      = (int2*)(ws + alloc((size_t)E * 8));

  int SGB = (N + 63) >> 6;
  int SCB = (E + 255) / 256;

  hipMemsetAsync(counts, 0, (size_t)N * 4, stream);
  prep_hist_kernel<<<128 + (E + 255) / 256, 256, 0, stream>>>(
      W1, W2, ei, counts, rank, w12t, w1eA, w2t, E);
  scan_kernel<<<1, 1024, 0, stream>>>(counts, row_ptr, N);
  scatter_sg_kernel<<<SGB + SCB, 256, 0, stream>>>(
      ei, row_ptr, rank, h, w12t, b1, ec, s2, g2, N, E);
  layer1_kernel<<<N, 128, 0, stream>>>(s2, g2, ef, ec, w1eA, row_ptr, hsumb);
  out_kernel<<<(N + 63) / 64, 256, 0, stream>>>(hsumb, w2t, b2, row_ptr, out, N);
}